// Round 1
// baseline (152.085 us; speedup 1.0000x reference)
//
#include <hip/hip_runtime.h>
#include <stdint.h>

// LowRankConv2d: out[b,o,h,w] = (1/9)*sum_{k,r,c} Hm[k,o,r]*G[k,r,c]*x[b,c,h+i-1,w+j-1] + bias[o]
// R6: (a) k_fused1 staging vectorized: f32x4 loads (16B/lane, 4x fewer VMEM instr), 64-pos
//     items, grid 784x1 (exact division, no 3.06-round tail);
//     (b) k_stage2: XCD-chunked bijective block mapping (each XCD owns exactly 2 batch
//     planes of T9 -> disjoint L2 footprints, kills cross-XCD tap-overlap refetch) and
//     2x16-pos tiles per iteration (4 independent MFMA chains, Bf amortized over 64 pos).

#define BATCH 16
#define CIN   256
#define COUT  256
#define RANK  32
#define HH    56
#define WW    56
#define SP    (HH*WW)        // 3136
#define YP    58
#define XP    58
#define PCELL (YP*XP)        // 3364
#define PLANE (BATCH*PCELL)

typedef __bf16 bf16x8 __attribute__((ext_vector_type(8)));
typedef float  f32x4  __attribute__((ext_vector_type(4)));

// ws layout (bytes):
//  T9   [9][16][58][58][32] bf16  = 31,002,624
//  G_bf [288][256] bf16           = 147,456
//  Hm_bf[9][256][32] bf16         = 147,456
#define OFF_T9 0
#define OFF_GB 31002624
#define OFF_HB (OFF_GB + 147456)

#define RING_U4 (9 * 16 * 228 * 4)   // border cells * 64B(=4 uint4)
#define PREP_N  (147456 + RING_U4)   // 278,784

__device__ __forceinline__ uint16_t bfbits(float f) {
  __bf16 h = (__bf16)f;
  return __builtin_bit_cast(uint16_t, h);
}

// weight casts + T9 border ring zero, one launch
__global__ __launch_bounds__(256) void k_prep(const float* __restrict__ G,
                                              const float* __restrict__ Hm,
                                              uint16_t* __restrict__ G_bf,
                                              uint16_t* __restrict__ Hm_bf,
                                              uint16_t* __restrict__ T9) {
  int i = blockIdx.x * 256 + threadIdx.x;
  if (i < 73728)  { G_bf[i] = bfbits(G[i]); return; }
  if (i < 147456) { Hm_bf[i - 73728] = bfbits(Hm[i - 73728]); return; }
  int j = i - 147456;
  if (j >= RING_U4) return;
  int v = j & 3, cell = j >> 2;
  int tb = cell / 228, c = cell % 228;
  int y, xx;
  if      (c < 58)  { y = 0;       xx = c;       }
  else if (c < 116) { y = 57;      xx = c - 58;  }
  else if (c < 172) { y = c - 115; xx = 0;       }
  else              { y = c - 171; xx = 57;      }
  uint16_t* base = T9 + ((size_t)tb * PCELL + y * XP + xx) * 32;
  uint4 z; z.x = z.y = z.z = z.w = 0u;
  ((uint4*)base)[v] = z;
}

// Fused transpose+cast+stage1: T9[tap][cell][r] = sum_c G[tap*32+r][c] * x[b][c][s]
// Block: 384 thr (6 waves); wave w holds G rows 48w..48w+47 reg-resident (24 frags).
// One item per block: (b, 64-pos chunk). Stage x into LDS bf16 [64 s][264 c-padded]
// via f32x4 loads (16B/lane, 4 positions) + register repack, then 4 n-tiles of 16 pos:
// 8x ds_read_b128 B-frags, 24 MFMA, 3 uint2 stores per wave per tile.
__global__ __launch_bounds__(384, 3) void k_fused1(const float* __restrict__ x,
                                                   const uint16_t* __restrict__ G_bf,
                                                   uint16_t* __restrict__ T9) {
  __shared__ uint16_t xs[64 * 264];
  const int tid = threadIdx.x;
  const int wave = tid >> 6, lane = tid & 63;
  const int q = lane >> 4, t = lane & 15;

  const int b  = blockIdx.x / 49;
  const int ch = blockIdx.x - b * 49;              // 49 chunks of 64 positions per batch

  bf16x8 A[3][8];
  {
    const uint16_t* gb = G_bf + (size_t)(wave * 48 + t) * CIN + q * 8;
#pragma unroll
    for (int i = 0; i < 3; ++i)
#pragma unroll
      for (int ks = 0; ks < 8; ++ks)
        A[i][ks] = *(const bf16x8*)(gb + (size_t)i * 16 * CIN + ks * 32);
  }

  // stage: 512 units = (cg 0..31, s4 0..15); unit loads 8 c-rows as f32x4 (4 positions),
  // repacks to 4x bf16x8 (one per position), writes 16B each. All loads 16B coalesced.
#pragma unroll 1
  for (int u = tid; u < 512; u += 384) {
    const int s4 = u & 15, cg = u >> 4;
    const float* xr = x + ((size_t)(b * CIN + cg * 8)) * SP + ch * 64 + s4 * 4;
    f32x4 f[8];
#pragma unroll
    for (int e = 0; e < 8; ++e)
      f[e] = *(const f32x4*)(xr + (size_t)e * SP);
#pragma unroll
    for (int p = 0; p < 4; ++p) {
      bf16x8 v;
#pragma unroll
      for (int e = 0; e < 8; ++e)
        ((__bf16*)&v)[e] = (__bf16)f[e][p];
      *(bf16x8*)&xs[(s4 * 4 + p) * 264 + cg * 8] = v;
    }
  }
  __syncthreads();

#pragma unroll 1
  for (int nt = 0; nt < 4; ++nt) {
    bf16x8 Bf[8];
#pragma unroll
    for (int ks = 0; ks < 8; ++ks)
      Bf[ks] = *(const bf16x8*)&xs[(nt * 16 + t) * 264 + ks * 32 + q * 8];

    f32x4 acc[3];
#pragma unroll
    for (int i = 0; i < 3; ++i) acc[i] = (f32x4){0.f, 0.f, 0.f, 0.f};
#pragma unroll
    for (int ks = 0; ks < 8; ++ks)
#pragma unroll
      for (int i = 0; i < 3; ++i)
        acc[i] = __builtin_amdgcn_mfma_f32_16x16x32_bf16(A[i][ks], Bf[ks], acc[i], 0, 0, 0);

    const int p = ch * 64 + nt * 16 + t;          // lane's store cell (D col = t)
    const int h = p / WW, w = p - (p / WW) * WW;
    const size_t cellbase = ((size_t)b * PCELL + (h + 1) * XP + (w + 1)) * 32;
#pragma unroll
    for (int i = 0; i < 3; ++i) {
      const int kr0 = wave * 48 + i * 16 + q * 4; // 4-run stays within one tap (4|32)
      const int tap = kr0 >> 5, r = kr0 & 31;
      uint2 pv;
      pv.x = (uint32_t)bfbits(acc[i][0]) | ((uint32_t)bfbits(acc[i][1]) << 16);
      pv.y = (uint32_t)bfbits(acc[i][2]) | ((uint32_t)bfbits(acc[i][3]) << 16);
      *(uint2*)(T9 + (size_t)tap * PLANE * 32 + cellbase + r) = pv;
    }
  }
}

// Stage 2: out[p][o] = (1/9)*sum_tap sum_r T9[tap][cell(p)+shift][r]*Hm[tap][o][r] + bias[o]
// Block: 512 thr (8 waves); wave w owns o in [32w, 32w+32): Bf[9][2] reg-resident (72 VGPR).
// Grid 784 = 8 XCDs x 98 blocks; block (xcd, pr) handles double-tiles
// mt2 = xcd*196 + pr*2 + {0,1} -> each XCD covers exactly 2 batch planes (196*32 = 2*SP
// positions), so tap-shifted T9 reuse stays inside one XCD's L2. Per double-tile: 2 A-frags
// per tap -> 4 independent MFMA chains. All 8 waves read identical A-tiles (L1-shared).
__global__ __launch_bounds__(512, 4) void k_stage2(const uint16_t* __restrict__ T9,
                                                   const uint16_t* __restrict__ Hm_bf,
                                                   const float* __restrict__ bias,
                                                   float* __restrict__ out) {
  const int wave = threadIdx.x >> 6, lane = threadIdx.x & 63;
  const int q = lane >> 4, t = lane & 15;

  const int bid = (int)blockIdx.x;
  const int xcd = bid & 7, pr = bid >> 3;         // 8 XCDs x 98 pair-slots
  const int mt2base = xcd * 196 + pr * 2;

  bf16x8 Bf[9][2];
  float bv[2];
#pragma unroll
  for (int j = 0; j < 2; ++j) {
    const int o = wave * 32 + j * 16 + t;
    bv[j] = bias[o];
#pragma unroll
    for (int tap = 0; tap < 9; ++tap)
      Bf[tap][j] = *(const bf16x8*)(Hm_bf + ((size_t)(tap * COUT + o)) * RANK + q * 8);
  }

#pragma unroll 1
  for (int it = 0; it < 2; ++it) {
    const int mt2 = mt2base + it;
    const int p0 = mt2 * 32;
    const int b = p0 / SP, s0 = p0 - b * SP;      // both 16-tiles stay in batch b (32|SP)

    const uint16_t* abase0;
    const uint16_t* abase1;
    {
      const int sa0 = s0 + t;
      const int ha0 = sa0 / WW, wa0 = sa0 - ha0 * WW;
      abase0 = T9 + ((size_t)(b * PCELL + ha0 * XP + wa0)) * 32 + q * 8;
      const int sa1 = s0 + 16 + t;
      const int ha1 = sa1 / WW, wa1 = sa1 - ha1 * WW;
      abase1 = T9 + ((size_t)(b * PCELL + ha1 * XP + wa1)) * 32 + q * 8;
    }

    f32x4 acc00 = (f32x4){0.f, 0.f, 0.f, 0.f};
    f32x4 acc01 = (f32x4){0.f, 0.f, 0.f, 0.f};
    f32x4 acc10 = (f32x4){0.f, 0.f, 0.f, 0.f};
    f32x4 acc11 = (f32x4){0.f, 0.f, 0.f, 0.f};
#pragma unroll
    for (int tap = 0; tap < 9; ++tap) {
      const int di = tap / 3, dj = tap % 3;
      const size_t toff = (size_t)tap * PLANE * 32 + (di * XP + dj) * 32;
      bf16x8 a0 = *(const bf16x8*)(abase0 + toff);
      bf16x8 a1 = *(const bf16x8*)(abase1 + toff);
      acc00 = __builtin_amdgcn_mfma_f32_16x16x32_bf16(a0, Bf[tap][0], acc00, 0, 0, 0);
      acc01 = __builtin_amdgcn_mfma_f32_16x16x32_bf16(a0, Bf[tap][1], acc01, 0, 0, 0);
      acc10 = __builtin_amdgcn_mfma_f32_16x16x32_bf16(a1, Bf[tap][0], acc10, 0, 0, 0);
      acc11 = __builtin_amdgcn_mfma_f32_16x16x32_bf16(a1, Bf[tap][1], acc11, 0, 0, 0);
    }

    const int sd0 = s0 + q * 4;                   // D rows = 4 consecutive positions
    const int sd1 = s0 + 16 + q * 4;
#pragma unroll
    for (int j = 0; j < 2; ++j) {
      const int o = wave * 32 + j * 16 + t;
      float* orow = out + ((size_t)(b * COUT + o)) * SP;
      f32x4 v0 = (j == 0 ? acc00 : acc01) * (1.0f / 9.0f) + bv[j];
      f32x4 v1 = (j == 0 ? acc10 : acc11) * (1.0f / 9.0f) + bv[j];
      *(f32x4*)(orow + sd0) = v0;
      *(f32x4*)(orow + sd1) = v1;
    }
  }
}

extern "C" void kernel_launch(void* const* d_in, const int* in_sizes, int n_in,
                              void* d_out, int out_size, void* d_ws, size_t ws_size,
                              hipStream_t stream) {
  const float* x    = (const float*)d_in[0];
  const float* G    = (const float*)d_in[1];
  const float* Hm   = (const float*)d_in[2];
  const float* bias = (const float*)d_in[3];
  float* out = (float*)d_out;
  char* ws = (char*)d_ws;

  uint16_t* T9    = (uint16_t*)(ws + OFF_T9);
  uint16_t* G_bf  = (uint16_t*)(ws + OFF_GB);
  uint16_t* Hm_bf = (uint16_t*)(ws + OFF_HB);

  k_prep<<<PREP_N / 256, 256, 0, stream>>>(G, Hm, G_bf, Hm_bf, T9);
  k_fused1<<<784, 384, 0, stream>>>(x, G_bf, T9);
  k_stage2<<<784, 512, 0, stream>>>(T9, Hm_bf, bias, out);
}

// Round 2
// 137.345 us; speedup vs baseline: 1.1073x; 1.1073x over previous
//
#include <hip/hip_runtime.h>
#include <stdint.h>

// LowRankConv2d: out[b,o,h,w] = (1/9)*sum_{k,r,c} Hm[k,o,r]*G[k,r,c]*x[b,c,h+i-1,w+j-1] + bias[o]
// R7: exact R5 structure (512-block persistent grids, 32-pos items) + ONE change:
//     k_fused1 staging uses f32x4 loads (16B/lane, 4x fewer VMEM instr, 4-row units
//     -> only 16 VGPR of staging state) instead of 8x scalar global_load_dword.
//     R6's grid restructure + XCD swizzle reverted (post-mortem: T9 has zero inter-block
//     reuse -> no L2 locality to win; fixed 784-grid had 1.31x makespan tail vs 1.14x).

#define BATCH 16
#define CIN   256
#define COUT  256
#define RANK  32
#define HH    56
#define WW    56
#define SP    (HH*WW)        // 3136
#define YP    58
#define XP    58
#define PCELL (YP*XP)        // 3364
#define PLANE (BATCH*PCELL)

typedef __bf16 bf16x8 __attribute__((ext_vector_type(8)));
typedef __bf16 bf16x4 __attribute__((ext_vector_type(4)));
typedef float  f32x4  __attribute__((ext_vector_type(4)));

// ws layout (bytes):
//  T9   [9][16][58][58][32] bf16  = 31,002,624
//  G_bf [288][256] bf16           = 147,456
//  Hm_bf[9][256][32] bf16         = 147,456
#define OFF_T9 0
#define OFF_GB 31002624
#define OFF_HB (OFF_GB + 147456)

#define RING_U4 (9 * 16 * 228 * 4)   // border cells * 64B(=4 uint4)
#define PREP_N  (147456 + RING_U4)   // 278,784

__device__ __forceinline__ uint16_t bfbits(float f) {
  __bf16 h = (__bf16)f;
  return __builtin_bit_cast(uint16_t, h);
}

// weight casts + T9 border ring zero, one launch
__global__ __launch_bounds__(256) void k_prep(const float* __restrict__ G,
                                              const float* __restrict__ Hm,
                                              uint16_t* __restrict__ G_bf,
                                              uint16_t* __restrict__ Hm_bf,
                                              uint16_t* __restrict__ T9) {
  int i = blockIdx.x * 256 + threadIdx.x;
  if (i < 73728)  { G_bf[i] = bfbits(G[i]); return; }
  if (i < 147456) { Hm_bf[i - 73728] = bfbits(Hm[i - 73728]); return; }
  int j = i - 147456;
  if (j >= RING_U4) return;
  int v = j & 3, cell = j >> 2;
  int tb = cell / 228, c = cell % 228;
  int y, xx;
  if      (c < 58)  { y = 0;       xx = c;       }
  else if (c < 116) { y = 57;      xx = c - 58;  }
  else if (c < 172) { y = c - 115; xx = 0;       }
  else              { y = c - 171; xx = 57;      }
  uint16_t* base = T9 + ((size_t)tb * PCELL + y * XP + xx) * 32;
  uint4 z; z.x = z.y = z.z = z.w = 0u;
  ((uint4*)base)[v] = z;
}

// Fused transpose+cast+stage1: T9[tap][cell][r] = sum_c G[tap*32+r][c] * x[b][c][s]
// Block: 384 thr (6 waves); wave w holds G rows 48w..48w+47 reg-resident (24 frags).
// Per item (b, 32-pos chunk): stage x into LDS bf16 [32 s][264 c-padded] via f32x4
// loads (unit = 4 positions x 4 c-rows: 4x global_load_dwordx4 + 16 cvt + 4x
// ds_write_b64), then 2 n-tiles of 16 pos: 8x ds_read_b128 B-frags, 24 MFMA,
// 3 uint2 stores per wave.
__global__ __launch_bounds__(384, 3) void k_fused1(const float* __restrict__ x,
                                                   const uint16_t* __restrict__ G_bf,
                                                   uint16_t* __restrict__ T9) {
  __shared__ uint16_t xs[32 * 264];
  const int tid = threadIdx.x;
  const int wave = tid >> 6, lane = tid & 63;
  const int q = lane >> 4, t = lane & 15;

  bf16x8 A[3][8];
  {
    const uint16_t* gb = G_bf + (size_t)(wave * 48 + t) * CIN + q * 8;
#pragma unroll
    for (int i = 0; i < 3; ++i)
#pragma unroll
      for (int ks = 0; ks < 8; ++ks)
        A[i][ks] = *(const bf16x8*)(gb + (size_t)i * 16 * CIN + ks * 32);
  }

#pragma unroll 1
  for (int item = blockIdx.x; item < 1568; item += 512) {
    const int b = item / 98, ch = item - b * 98;    // 98 chunks of 32 positions per batch

    // stage: 512 units = (s4 0..7, c4 0..63); unit loads 4 c-rows as f32x4 (4 positions
    // each, 16B coalesced), repacks to 4x bf16x4 (one per position), writes 8B each.
#pragma unroll 1
    for (int u = tid; u < 512; u += 384) {
      const int s4 = u & 7, c4 = u >> 3;
      const int c0 = c4 * 4;
      const float* xr = x + ((size_t)(b * CIN + c0)) * SP + ch * 32 + s4 * 4;
      f32x4 f[4];
#pragma unroll
      for (int e = 0; e < 4; ++e)
        f[e] = *(const f32x4*)(xr + (size_t)e * SP);
#pragma unroll
      for (int p = 0; p < 4; ++p) {
        bf16x4 v;
#pragma unroll
        for (int e = 0; e < 4; ++e)
          ((__bf16*)&v)[e] = (__bf16)f[e][p];
        *(bf16x4*)&xs[(s4 * 4 + p) * 264 + c0] = v;
      }
    }
    __syncthreads();

#pragma unroll 1
    for (int nt = 0; nt < 2; ++nt) {
      bf16x8 Bf[8];
#pragma unroll
      for (int ks = 0; ks < 8; ++ks)
        Bf[ks] = *(const bf16x8*)&xs[(nt * 16 + t) * 264 + ks * 32 + q * 8];

      f32x4 acc[3];
#pragma unroll
      for (int i = 0; i < 3; ++i) acc[i] = (f32x4){0.f, 0.f, 0.f, 0.f};
#pragma unroll
      for (int ks = 0; ks < 8; ++ks)
#pragma unroll
        for (int i = 0; i < 3; ++i)
          acc[i] = __builtin_amdgcn_mfma_f32_16x16x32_bf16(A[i][ks], Bf[ks], acc[i], 0, 0, 0);

      const int p = ch * 32 + nt * 16 + t;          // lane's store cell (D col = t)
      const int h = p / WW, w = p - (p / WW) * WW;
      const size_t cellbase = ((size_t)b * PCELL + (h + 1) * XP + (w + 1)) * 32;
#pragma unroll
      for (int i = 0; i < 3; ++i) {
        const int kr0 = wave * 48 + i * 16 + q * 4; // 4-run stays within one tap (4|32)
        const int tap = kr0 >> 5, r = kr0 & 31;
        uint2 pv;
        pv.x = (uint32_t)bfbits(acc[i][0]) | ((uint32_t)bfbits(acc[i][1]) << 16);
        pv.y = (uint32_t)bfbits(acc[i][2]) | ((uint32_t)bfbits(acc[i][3]) << 16);
        *(uint2*)(T9 + (size_t)tap * PLANE * 32 + cellbase + r) = pv;
      }
    }
    __syncthreads();
  }
}

// Stage 2: out[p][o] = (1/9)*sum_tap sum_r T9[tap][cell(p)+shift][r]*Hm[tap][o][r] + bias[o]
// Block: 512 thr (8 waves); wave w owns o in [32w, 32w+32): Bf[9][2] reg-resident (72 VGPR)
// -> 16 waves/CU. All 8 waves read identical T9 A-tiles (L1-shared). Persistent grid 512.
__global__ __launch_bounds__(512, 4) void k_stage2(const uint16_t* __restrict__ T9,
                                                   const uint16_t* __restrict__ Hm_bf,
                                                   const float* __restrict__ bias,
                                                   float* __restrict__ out) {
  const int wave = threadIdx.x >> 6, lane = threadIdx.x & 63;
  const int q = lane >> 4, t = lane & 15;

  bf16x8 Bf[9][2];
  float bv[2];
#pragma unroll
  for (int j = 0; j < 2; ++j) {
    const int o = wave * 32 + j * 16 + t;
    bv[j] = bias[o];
#pragma unroll
    for (int tap = 0; tap < 9; ++tap)
      Bf[tap][j] = *(const bf16x8*)(Hm_bf + ((size_t)(tap * COUT + o)) * RANK + q * 8);
  }

#pragma unroll 1
  for (int mt = blockIdx.x; mt < 3136; mt += 512) {
    const int p0 = mt * 16;
    const int b = p0 / SP, s0 = p0 - b * SP;
    const int sa = s0 + t;
    const int ha = sa / WW, wa = sa - ha * WW;
    const uint16_t* abase = T9 + ((size_t)(b * PCELL + ha * XP + wa)) * 32 + q * 8;

    f32x4 acc[2];
    acc[0] = (f32x4){0.f, 0.f, 0.f, 0.f};
    acc[1] = (f32x4){0.f, 0.f, 0.f, 0.f};
#pragma unroll
    for (int tap = 0; tap < 9; ++tap) {
      const int di = tap / 3, dj = tap % 3;
      bf16x8 af = *(const bf16x8*)(abase + (size_t)tap * PLANE * 32 + (di * XP + dj) * 32);
      acc[0] = __builtin_amdgcn_mfma_f32_16x16x32_bf16(af, Bf[0 + tap][0], acc[0], 0, 0, 0);
      acc[1] = __builtin_amdgcn_mfma_f32_16x16x32_bf16(af, Bf[0 + tap][1], acc[1], 0, 0, 0);
    }

    const int sd = s0 + q * 4;                      // D rows = 4 consecutive positions
#pragma unroll
    for (int j = 0; j < 2; ++j) {
      const int o = wave * 32 + j * 16 + t;
      f32x4 v = acc[j] * (1.0f / 9.0f) + bv[j];
      *(f32x4*)(out + ((size_t)(b * COUT + o)) * SP + sd) = v;
    }
  }
}

extern "C" void kernel_launch(void* const* d_in, const int* in_sizes, int n_in,
                              void* d_out, int out_size, void* d_ws, size_t ws_size,
                              hipStream_t stream) {
  const float* x    = (const float*)d_in[0];
  const float* G    = (const float*)d_in[1];
  const float* Hm   = (const float*)d_in[2];
  const float* bias = (const float*)d_in[3];
  float* out = (float*)d_out;
  char* ws = (char*)d_ws;

  uint16_t* T9    = (uint16_t*)(ws + OFF_T9);
  uint16_t* G_bf  = (uint16_t*)(ws + OFF_GB);
  uint16_t* Hm_bf = (uint16_t*)(ws + OFF_HB);

  k_prep<<<PREP_N / 256, 256, 0, stream>>>(G, Hm, G_bf, Hm_bf, T9);
  k_fused1<<<512, 384, 0, stream>>>(x, G_bf, T9);
  k_stage2<<<512, 512, 0, stream>>>(T9, Hm_bf, bias, out);
}